// Round 1
// 239.525 us; speedup vs baseline: 1.0170x; 1.0170x over previous
//
#include <hip/hip_runtime.h>

#define PI_F 3.14159f

// ---------------------------------------------------------------------------
// Kernel A: per-batch MLP head -> per-channel PRE-SCALED affine params.
// 4 batches per block, 256 threads. Phase 1 keeps para in registers and
// broadcasts with v_readlane (no LDS). params layout: [B][20][8] =
// (P0..P5, 0, 0):  ix = P0*X + P1*Y + P2 ; iy = P3*X + P4*Y + P5
// with grid_sample *9+8.5 scaling and the +1 LDS-pad shift folded in.
// ---------------------------------------------------------------------------
__global__ __launch_bounds__(256) void params_kernel(
    const float* __restrict__ pc, const float* __restrict__ W1, const float* __restrict__ b1,
    const float* __restrict__ Ws, const float* __restrict__ bs,
    const float* __restrict__ Wr, const float* __restrict__ br,
    const float* __restrict__ Wt, const float* __restrict__ bt,
    float* __restrict__ params)
{
    __shared__ float hbuf[4][260];
    __shared__ float raw[4][80];

    const int t    = threadIdx.x;
    const int lane = t & 63;
    const int b0   = blockIdx.x * 4;

    float pval[4][4];
    #pragma unroll
    for (int g = 0; g < 4; ++g)
        #pragma unroll
        for (int c = 0; c < 4; ++c)
            pval[g][c] = pc[(size_t)(b0 + g) * 256 + c * 64 + lane];

    float acc[4];
    #pragma unroll
    for (int g = 0; g < 4; ++g) acc[g] = b1[t];

    #pragma unroll
    for (int c = 0; c < 4; ++c) {
        for (int kk = 0; kk < 64; ++kk) {
            float w = W1[(c * 64 + kk) * 256 + t];
            #pragma unroll
            for (int g = 0; g < 4; ++g) {
                float pk = __int_as_float(
                    __builtin_amdgcn_readlane(__float_as_int(pval[g][c]), kk));
                acc[g] = fmaf(pk, w, acc[g]);
            }
        }
    }
    #pragma unroll
    for (int g = 0; g < 4; ++g) hbuf[g][t] = fmaxf(acc[g], 0.0f);
    __syncthreads();

    for (int task = t; task < 320; task += 256) {
        int g   = task / 80;
        int col = task - g * 80;
        const float* Wcol;
        float bias;
        int stride;
        if (col < 20)      { Wcol = Ws + col;        bias = bs[col];      stride = 20; }
        else if (col < 40) { Wcol = Wr + (col - 20); bias = br[col - 20]; stride = 20; }
        else               { Wcol = Wt + (col - 40); bias = bt[col - 40]; stride = 40; }
        const float4* h4 = (const float4*)hbuf[g];
        float a = bias;
        for (int k4 = 0; k4 < 64; ++k4) {
            float4 h = h4[k4];
            int k = k4 * 4;
            a = fmaf(h.x, Wcol[k * stride], a);
            a = fmaf(h.y, Wcol[(k + 1) * stride], a);
            a = fmaf(h.z, Wcol[(k + 2) * stride], a);
            a = fmaf(h.w, Wcol[(k + 3) * stride], a);
        }
        raw[g][col] = a;
    }
    __syncthreads();

    for (int task = t; task < 80; task += 256) {
        int g = task / 20;
        int f = task - g * 20;
        float sc  = 2.0f / (1.0f + expf(-raw[g][f]));
        float ang = PI_F * tanhf(raw[g][20 + f]);
        float tx  = tanhf(raw[g][40 + 2 * f]);
        float ty  = tanhf(raw[g][40 + 2 * f + 1]);
        float c = cosf(ang), s = sinf(ang);
        float* o = params + ((size_t)(b0 + g) * 20 + f) * 8;
        o[0] = 9.0f * sc * c;  o[1] = -9.0f * sc * s;  o[2] = fmaf(9.0f, tx, 9.5f);
        o[3] = 9.0f * sc * s;  o[4] =  9.0f * sc * c;  o[5] = fmaf(9.0f, ty, 9.5f);
        o[6] = 0.0f;           o[7] = 0.0f;
    }
}

// ---------------------------------------------------------------------------
// Kernel B v2: one block per (batch, channel-half). Channels 0-9 sample only
// z-slices 0-9 and channels 10-19 only slices 10-19 (iz(f) = (40f-19)/38), so
// the split duplicates ZERO HBM reads. Per block: 10 slices staged z-blended
// into LDS [10][20][20] with a 1-cell zero pad; only the 76 border cells per
// channel (+24-float tail) are zeroed -> no barrier between zero and stage
// (disjoint cells). Params are read via wave-uniform scalar loads (s_load),
// no LDS round-trip. LDS = 4024 floats = 16,096 B; occupancy wave-limited at
// 5 blocks/CU (30/32 waves).
// ---------------------------------------------------------------------------
template<int CH0, int J>
struct Stage {
    static constexpr int   F   = CH0 + J;
    static constexpr int   Z0g = (F == 0) ? -1 : (40 * F - 19) / 38;
    static constexpr float W1v = (float)((40.0 * F - 19.0) / 38.0 - (double)Z0g);
    static constexpr float W0v = 1.0f - W1v;
    static constexpr int   S0  = Z0g - CH0;          // local slice index
    static constexpr bool  V0  = (Z0g >= 0);
    static constexpr bool  V1  = (Z0g + 1 <= 19);

    static __device__ __forceinline__ void go(const float (&v)[10], float* vol, int w) {
        float I;
        if constexpr (V0 && V1)  I = fmaf(v[S0], W0v, v[S0 + 1] * W1v);
        else if constexpr (V0)   I = v[S0] * W0v;
        else                     I = v[(S0 + 1) < 0 ? 0 : (S0 + 1)] * W1v;
        vol[J * 400 + w] = I;
        Stage<CH0, J + 1>::go(v, vol, w);
    }
};
template<int CH0> struct Stage<CH0, 10> {
    static __device__ __forceinline__ void go(const float (&)[10], float*, int) {}
};

template<int CH0>
__device__ __forceinline__ void sample_half(
    const float* __restrict__ fmap, const float* __restrict__ params,
    float* __restrict__ out, int b, int t, float* vol)
{
    int yy = 0, xx = 0;
    float v[10];
    // 1) issue the 10 coalesced slice loads FIRST (HBM latency overlaps zeroing)
    if (t < 324) {
        yy = t / 18;
        xx = t - yy * 18;
        const float* fb = fmap + (size_t)b * 6480 + CH0 * 324 + t;
        #pragma unroll
        for (int k = 0; k < 10; ++k) v[k] = fb[k * 324];
    }

    // 2) zero ONLY pad cells: rows 0,19 of each channel (100 float4) + 24-float
    //    tail (6 float4) + cols 0,19 rows 1..18 (360 scalars). Disjoint from
    //    the interior the stage writes -> no barrier needed in between.
    float4* v4 = (float4*)vol;
    for (int i = t; i < 106; i += 384) {
        int idx;
        if (i < 100) {
            int j = i / 10, r = i - j * 10;
            idx = j * 100 + (r < 5 ? r : 95 + (r - 5));
        } else {
            idx = 1000 + (i - 100);
        }
        v4[idx] = make_float4(0.f, 0.f, 0.f, 0.f);
    }
    for (int i = t; i < 360; i += 384) {
        int j = i / 36, r = i - j * 36;
        int y = 1 + (r < 18 ? r : r - 18);
        int x = (r < 18 ? 0 : 19);
        vol[j * 400 + y * 20 + x] = 0.0f;
    }

    // 3) z-blend into padded interior
    if (t < 324) {
        const int w = (yy + 1) * 20 + (xx + 1);
        Stage<CH0, 0>::go(v, vol, w);
    }
    __syncthreads();          // the ONLY barrier

    if (t >= 324) return;

    const float X = xx * (2.0f / 17.0f) - 1.0f;
    const float Y = yy * (2.0f / 17.0f) - 1.0f;
    float* ob = out + (size_t)b * 6480 + CH0 * 324 + t;
    const float* pp = params + ((size_t)b * 20 + CH0) * 8;   // wave-uniform

    float u1[10], w1_[10];
    int base[10];
    #pragma unroll
    for (int j = 0; j < 10; ++j) {
        float4 pA = *(const float4*)(pp + j * 8);     // uniform -> s_load_dwordx4
        float2 pB = *(const float2*)(pp + j * 8 + 4); // uniform -> s_load_dwordx2
        float ix = fmaf(pA.x, X, fmaf(pA.y, Y, pA.z));
        float iy = fmaf(pA.w, X, fmaf(pB.x, Y, pB.y));
        ix = fminf(fmaxf(ix, 0.0f), 19.0f);
        iy = fminf(fmaxf(iy, 0.0f), 19.0f);
        float fx = floorf(ix), fy = floorf(iy);
        u1[j]  = ix - fx;
        w1_[j] = iy - fy;
        base[j] = j * 400 + (int)fy * 20 + (int)fx;
    }
    float t00[10], t01[10], t10[10], t11[10];
    #pragma unroll
    for (int j = 0; j < 10; ++j) {
        const float* s = vol + base[j];               // 2x ds_read2_b32
        t00[j] = s[0]; t01[j] = s[1]; t10[j] = s[20]; t11[j] = s[21];
    }
    #pragma unroll
    for (int j = 0; j < 10; ++j) {
        float u0 = 1.0f - u1[j], v0 = 1.0f - w1_[j];
        float r = fmaf(fmaf(t01[j], u1[j], t00[j] * u0), v0,
                       fmaf(t11[j], u1[j], t10[j] * u0) * w1_[j]);
        ob[j * 324] = r;
    }
}

__global__ __launch_bounds__(384, 8) void sample_kernel(
    const float* __restrict__ fmap, const float* __restrict__ params,
    float* __restrict__ out)
{
    // [10][20][20] z-blended padded volume + 24-float tail so the weight-0
    // overreads at fy==19 on channel 9 stay in-bounds and finite.
    __shared__ __align__(16) float vol[4024];

    const int bid = blockIdx.x;
    const int b   = bid >> 1;
    const int t   = threadIdx.x;

    if (bid & 1) sample_half<10>(fmap, params, out, b, t, vol);
    else         sample_half<0>(fmap, params, out, b, t, vol);
}

extern "C" void kernel_launch(void* const* d_in, const int* in_sizes, int n_in,
                              void* d_out, int out_size, void* d_ws, size_t ws_size,
                              hipStream_t stream)
{
    const float* fmap = (const float*)d_in[0];
    const float* pc   = (const float*)d_in[1];
    const float* W1   = (const float*)d_in[2];
    const float* b1   = (const float*)d_in[3];
    const float* Ws   = (const float*)d_in[4];
    const float* bs   = (const float*)d_in[5];
    const float* Wr   = (const float*)d_in[6];
    const float* br   = (const float*)d_in[7];
    const float* Wt   = (const float*)d_in[8];
    const float* bt   = (const float*)d_in[9];
    float* out    = (float*)d_out;
    float* params = (float*)d_ws;     // B*20*8 floats

    const int B = in_sizes[0] / (20 * 18 * 18);   // 4096

    params_kernel<<<B / 4, 256, 0, stream>>>(pc, W1, b1, Ws, bs, Wr, br, Wt, bt, params);
    sample_kernel<<<B * 2, 384, 0, stream>>>(fmap, params, out);
}